// Round 8
// baseline (140.572 us; speedup 1.0000x reference)
//
#include <hip/hip_runtime.h>

// CrumbReconstructor R11: R10 (TPK=4 + row-split, lowest LDS + lowest
// per-key overhead at constant wave count) with the register starvation
// fixed and the merge/store tail balanced.
//
// R10 post-mortem: VGPR_Count=40 < sizeof(k[4][8])=32+rest -> key array was
// NOT register-resident under __launch_bounds__(128,6); WRITE_SIZE +3136KB
// (= 8B/thread spill eviction) and FETCH +0.8MB (L2 spill fills) confirm.
// The spill/reload traffic ate the 18% instruction saving (71->76us).
//
// Changes vs R10 (only these):
//  1. __launch_bounds__(128,4): VGPR cap 128; kb[]/valid[] dropped from the
//     loop live set (recomputed at store) -> full live set ~70 regs fits.
//  2. Both waves publish best/bidx; wave0 merges+stores t={0,1}, wave1
//     t={2,3} (R10 put the whole tail on wave0). Compile-time t indices
//     inside wave-uniform branches (no runtime-indexed register arrays).
//
// Exactness: per-row distance bit-identical to R3..R10 (sequential fmaf dot,
// fmaf(dot,-2,knorm)+rn). Within-half argmin uses strict < (first min wins);
// cross-half merge takes the hi half only on strictly smaller d — lo rows
// have strictly smaller indices, so this is exactly reference argmin.

#define LBLK 8          // memblock length
#define NROW 256        // codebook rows
#define HROW 128        // rows per wave (half of the row space)
#define BLOCK 128       // 2 waves per block (a lo/hi row pair)
#define TPK 4           // keys per thread; block covers 256 keys

__global__ __launch_bounds__(BLOCK, 4) void crumb_kernel(
    const float* __restrict__ x,
    const float* __restrict__ mem,
    float* __restrict__ out,
    int nblocks)
{
    __shared__ float s_mem[NROW * LBLK];   // 8 KB, rows contiguous
    __shared__ float s_norm[NROW];         // 1 KB
    __shared__ float s_pbest[2][256];      // per-wave published best
    __shared__ int   s_pbidx[2][256];      // per-wave published argmin

    const int tid = threadIdx.x;

    // --- stage codebook: 2 rows per thread, coalesced (R3-proven) ---
    {
        const float4* g = (const float4*)mem;
        #pragma unroll
        for (int c = 0; c < 2; ++c) {
            const int rr = c * BLOCK + tid;
            float4 a = g[rr * 2 + 0];
            float4 b = g[rr * 2 + 1];
            ((float4*)s_mem)[rr * 2 + 0] = a;
            ((float4*)s_mem)[rr * 2 + 1] = b;
            float q0 = a.x * a.x, q1 = a.y * a.y, q2 = a.z * a.z, q3 = a.w * a.w;
            float q4 = b.x * b.x, q5 = b.y * b.y, q6 = b.z * b.z, q7 = b.w * b.w;
            s_norm[rr] = ((q0 + q1) + (q2 + q3)) + ((q4 + q5) + (q6 + q7));
        }
    }
    __syncthreads();

    const int lane = tid & 63;
    const int wid  = tid >> 6;      // 0: rows 0..127, 1: rows 128..255

    // --- load the block's 256 keys (both waves load the same keys) ---
    float k[TPK][LBLK];
    float knorm[TPK];

    #pragma unroll
    for (int t = 0; t < TPK; ++t) {
        long b0 = (long)blockIdx.x * 256 + t * 64 + lane;
        long kbt = (b0 < (long)nblocks) ? b0 : 0;   // transient, not loop-live
        const float4* g = (const float4*)(x + kbt * LBLK);
        float4 a = g[0], b = g[1];
        k[t][0] = a.x; k[t][1] = a.y; k[t][2] = a.z; k[t][3] = a.w;
        k[t][4] = b.x; k[t][5] = b.y; k[t][6] = b.z; k[t][7] = b.w;
        float q0 = a.x * a.x, q1 = a.y * a.y, q2 = a.z * a.z, q3 = a.w * a.w;
        float q4 = b.x * b.x, q5 = b.y * b.y, q6 = b.z * b.z, q7 = b.w * b.w;
        knorm[t] = ((q0 + q1) + (q2 + q3)) + ((q4 + q5) + (q6 + q7));
    }

    float best[TPK];
    int   bidx[TPK];
    #pragma unroll
    for (int t = 0; t < TPK; ++t) { best[t] = 3.4e38f; bidx[t] = 0; }

    // --- scan this wave's 128 rows; R3's rotation prefetch, 1 row ahead ---
    const int rbase = wid * HROW;
    const float4* sm4 = (const float4*)s_mem;

    float4 ra = sm4[rbase * 2 + 0];
    float4 rb = sm4[rbase * 2 + 1];
    float  rn = s_norm[rbase];

    #pragma unroll 4
    for (int r = 0; r < HROW; ++r) {
        const int rr = rbase + ((r + 1) & (HROW - 1));   // wraps in-half
        float4 na = sm4[rr * 2 + 0];
        float4 nb = sm4[rr * 2 + 1];
        float  nn = s_norm[rr];
        const int m = rbase + r;

        #pragma unroll
        for (int t = 0; t < TPK; ++t) {
            float dot = k[t][0] * ra.x;
            dot = fmaf(k[t][1], ra.y, dot);
            dot = fmaf(k[t][2], ra.z, dot);
            dot = fmaf(k[t][3], ra.w, dot);
            dot = fmaf(k[t][4], rb.x, dot);
            dot = fmaf(k[t][5], rb.y, dot);
            dot = fmaf(k[t][6], rb.z, dot);
            dot = fmaf(k[t][7], rb.w, dot);
            float d = fmaf(dot, -2.0f, knorm[t]) + rn;
            // strict < : first (lowest) index wins exact ties (= argmin)
            if (d < best[t]) { best[t] = d; bidx[t] = m; }
        }

        ra = na; rb = nb; rn = nn;
    }

    // --- publish all results; each wave merges + stores its half of keys ---
    #pragma unroll
    for (int t = 0; t < TPK; ++t) {
        s_pbest[wid][t * 64 + lane] = best[t];
        s_pbidx[wid][t * 64 + lane] = bidx[t];
    }
    __syncthreads();

    // lo rows (0..127) have strictly smaller indices than hi rows:
    //   take hi ONLY on strictly smaller distance -> exact first-min argmin.
#define MERGE_STORE_LO(T)                                               \
    {                                                                   \
        float od = s_pbest[1][(T) * 64 + lane];                         \
        int   ob = s_pbidx[1][(T) * 64 + lane];                         \
        int   fb = (od < best[(T)]) ? ob : bidx[(T)];                   \
        long  b0 = (long)blockIdx.x * 256 + (T) * 64 + lane;            \
        if (b0 < (long)nblocks) {                                       \
            float4* o = (float4*)(out + b0 * LBLK);                     \
            o[0] = sm4[fb * 2 + 0];                                     \
            o[1] = sm4[fb * 2 + 1];                                     \
        }                                                               \
    }
#define MERGE_STORE_HI(T)                                               \
    {                                                                   \
        float od = s_pbest[0][(T) * 64 + lane];                         \
        int   ob = s_pbidx[0][(T) * 64 + lane];                         \
        int   fb = (best[(T)] < od) ? bidx[(T)] : ob;                   \
        long  b0 = (long)blockIdx.x * 256 + (T) * 64 + lane;            \
        if (b0 < (long)nblocks) {                                       \
            float4* o = (float4*)(out + b0 * LBLK);                     \
            o[0] = sm4[fb * 2 + 0];                                     \
            o[1] = sm4[fb * 2 + 1];                                     \
        }                                                               \
    }

    if (wid == 0) {
        MERGE_STORE_LO(0);
        MERGE_STORE_LO(1);
    } else {
        MERGE_STORE_HI(2);
        MERGE_STORE_HI(3);
    }
#undef MERGE_STORE_LO
#undef MERGE_STORE_HI
}

extern "C" void kernel_launch(void* const* d_in, const int* in_sizes, int n_in,
                              void* d_out, int out_size, void* d_ws, size_t ws_size,
                              hipStream_t stream) {
    const float* x   = (const float*)d_in[0];
    const float* mem = (const float*)d_in[1];
    float* out = (float*)d_out;

    int n = in_sizes[0];            // total x elements
    int nblocks = n / LBLK;         // key-blocks (802816 for std shape)
    int grid = (nblocks + 255) / 256;   // 3136 for std shape

    hipLaunchKernelGGL(crumb_kernel, dim3(grid), dim3(BLOCK), 0, stream,
                       x, mem, out, nblocks);
}

// Round 9
// 128.768 us; speedup vs baseline: 1.0917x; 1.0917x over previous
//
#include <hip/hip_runtime.h>

// CrumbReconstructor R12: R3 champion structure (TPK=2, BLOCK=256, LDS
// broadcast) with the two reducible per-row costs removed:
//   (a) rotation movs (9/row in R3) -> flat window-8 loads, no ring;
//   (b) half the argmin bookkeeping -> group-8 min tree + once-per-key
//       exact resolve of the winning group.
//
// R10/R11 post-mortem: TPK=4 row-split is un-shapeable from HIP — compiler
// pins arch-VGPR at 40 and shuffles the key array through AGPRs regardless
// of __launch_bounds__; abandoned. R3 cycle budget/row: 40 math-cy + 18
// mov-cy + 12 bookkeep-cy + ~7 LDS/loop = 77cy -> 50us floor, 71 measured.
// This kernel: ~49cy/row -> ~32us floor, predict 50-62us.
//
// Exactness (absmax must stay 0.0):
//  - each distance d uses the identical fp32 sequence (mul, 7x fmaf,
//    fmaf(dot,-2,knorm), + rn) -> bit-identical values;
//  - group min value is order-independent (no NaN possible); strict
//    (gmin < best) keeps the FIRST group attaining the global min;
//  - resolve recomputes the 8 group distances bit-identically and takes
//    the first j with d == best -> exact reference first-index argmin.

#define LBLK 8          // memblock length
#define NROW 256        // codebook rows
#define BLOCK 256       // 4 waves per block
#define TPK 2           // keys per thread
#define WIN 8           // rows per window / argmin group

typedef float f32x2 __attribute__((ext_vector_type(2)));

__global__ __launch_bounds__(BLOCK, 2) void crumb_kernel(
    const float* __restrict__ x,
    const float* __restrict__ mem,
    float* __restrict__ out,
    int nblocks)
{
    __shared__ float s_mem[NROW * LBLK];            // 8 KB, rows contiguous
    __shared__ __align__(8) float s_norm[NROW];     // 1 KB, b64-pair reads

    const int tid = threadIdx.x;

    // --- stage codebook: thread t loads row t, computes its norm ---
    {
        const float4* g = (const float4*)mem;
        float4 a = g[tid * 2 + 0];
        float4 b = g[tid * 2 + 1];
        ((float4*)s_mem)[tid * 2 + 0] = a;
        ((float4*)s_mem)[tid * 2 + 1] = b;
        float q0 = a.x * a.x, q1 = a.y * a.y, q2 = a.z * a.z, q3 = a.w * a.w;
        float q4 = b.x * b.x, q5 = b.y * b.y, q6 = b.z * b.z, q7 = b.w * b.w;
        s_norm[tid] = ((q0 + q1) + (q2 + q3)) + ((q4 + q5) + (q6 + q7));
    }
    __syncthreads();

    // --- load 2 keys per thread (R3 pattern) ---
    const long base = (long)blockIdx.x * (BLOCK * TPK) + tid;

    float k[TPK][LBLK];
    float knorm[TPK];
    long  kb[TPK];
    bool  valid[TPK];

    #pragma unroll
    for (int t = 0; t < TPK; ++t) {
        long b0 = base + (long)t * BLOCK;
        valid[t] = (b0 < (long)nblocks);
        kb[t] = valid[t] ? b0 : 0;
        const float4* g = (const float4*)(x + kb[t] * LBLK);
        float4 a = g[0], b = g[1];
        k[t][0] = a.x; k[t][1] = a.y; k[t][2] = a.z; k[t][3] = a.w;
        k[t][4] = b.x; k[t][5] = b.y; k[t][6] = b.z; k[t][7] = b.w;
        float q0 = a.x * a.x, q1 = a.y * a.y, q2 = a.z * a.z, q3 = a.w * a.w;
        float q4 = b.x * b.x, q5 = b.y * b.y, q6 = b.z * b.z, q7 = b.w * b.w;
        knorm[t] = ((q0 + q1) + (q2 + q3)) + ((q4 + q5) + (q6 + q7));
    }

    float best[TPK];
    int   gbase[TPK];
    #pragma unroll
    for (int t = 0; t < TPK; ++t) { best[t] = 3.4e38f; gbase[t] = 0; }

    const float4* sm4 = (const float4*)s_mem;

    // the exact reference distance chain (bit-identical everywhere)
#define DIST(T, RA, RB, RN, DST)                                        \
    {                                                                   \
        float dot = k[(T)][0] * (RA).x;                                 \
        dot = fmaf(k[(T)][1], (RA).y, dot);                             \
        dot = fmaf(k[(T)][2], (RA).z, dot);                             \
        dot = fmaf(k[(T)][3], (RA).w, dot);                             \
        dot = fmaf(k[(T)][4], (RB).x, dot);                             \
        dot = fmaf(k[(T)][5], (RB).y, dot);                             \
        dot = fmaf(k[(T)][6], (RB).z, dot);                             \
        dot = fmaf(k[(T)][7], (RB).w, dot);                             \
        (DST) = fmaf(dot, -2.0f, knorm[(T)]) + (RN);                    \
    }

    // --- scan: 8-row windows, flat loads (no rotation), group-8 argmin ---
    #pragma unroll 1
    for (int r = 0; r < NROW; r += WIN) {
        float4 A[WIN], B[WIN];
        float  N[WIN];
        #pragma unroll
        for (int j = 0; j < WIN; ++j) {
            A[j] = sm4[(r + j) * 2 + 0];
            B[j] = sm4[(r + j) * 2 + 1];
        }
        #pragma unroll
        for (int j = 0; j < WIN; j += 2) {
            f32x2 np = *(const f32x2*)&s_norm[r + j];
            N[j] = np.x; N[j + 1] = np.y;
        }

        #pragma unroll
        for (int t = 0; t < TPK; ++t) {
            float d[WIN];
            #pragma unroll
            for (int j = 0; j < WIN; ++j) DIST(t, A[j], B[j], N[j], d[j]);
            // group min (value is order-independent; no NaN possible)
            float g = fminf(fminf(fminf(d[0], d[1]), fminf(d[2], d[3])),
                            fminf(fminf(d[4], d[5]), fminf(d[6], d[7])));
            // strict < : FIRST group attaining the global min wins
            if (g < best[t]) { best[t] = g; gbase[t] = r; }
        }
    }

    // --- resolve: recompute winning group bit-identically, first d==best ---
    int fidx[TPK];
    #pragma unroll
    for (int t = 0; t < TPK; ++t) {
        const int gb = gbase[t];
        int  fi = gb;
        bool found = false;
        #pragma unroll
        for (int j = 0; j < WIN; ++j) {
            float4 a = sm4[(gb + j) * 2 + 0];
            float4 b = sm4[(gb + j) * 2 + 1];
            float  nn = s_norm[gb + j];
            float  d;
            DIST(t, a, b, nn, d);
            bool hit = (d == best[t]);
            if (hit && !found) fi = gb + j;   // first match = lowest index
            found = found || hit;
        }
        fidx[t] = fi;
    }
#undef DIST

    // --- gather winning rows from LDS, store ---
    #pragma unroll
    for (int t = 0; t < TPK; ++t) {
        if (valid[t]) {
            float4* o = (float4*)(out + kb[t] * LBLK);
            o[0] = sm4[fidx[t] * 2 + 0];
            o[1] = sm4[fidx[t] * 2 + 1];
        }
    }
}

extern "C" void kernel_launch(void* const* d_in, const int* in_sizes, int n_in,
                              void* d_out, int out_size, void* d_ws, size_t ws_size,
                              hipStream_t stream) {
    const float* x   = (const float*)d_in[0];
    const float* mem = (const float*)d_in[1];
    float* out = (float*)d_out;

    int n = in_sizes[0];            // total x elements
    int nblocks = n / LBLK;         // key-blocks (802816 for std shape)
    int grid = (nblocks + BLOCK * TPK - 1) / (BLOCK * TPK);   // 1568

    hipLaunchKernelGGL(crumb_kernel, dim3(grid), dim3(BLOCK), 0, stream,
                       x, mem, out, nblocks);
}